// Round 1
// baseline (5022.721 us; speedup 1.0000x reference)
//
#include <hip/hip_runtime.h>
#include <math.h>

#define MQ 512           // states q
#define ML 512           // sequence length L
#define MS 26            // symbols
#define MB 32            // batch
#define MM 2             // models
#define NPOST (MM*MB*ML*MQ)   // 16777216

// ws layout (floats)
#define OFF_A    0
#define OFF_AT   (OFF_A + MM*MQ*MQ)
#define OFF_B    (OFF_AT + MM*MQ*MQ)
#define OFF_INIT (OFF_B + MM*MQ*MS)
#define OFF_E    (OFF_INIT + MM*MQ)
#define OFF_P1   (OFF_E + NPOST)
#define OFF_LL   (OFF_P1 + NPOST)

// ---------------- row softmax of transition logits -> A (prob domain) ----------------
__global__ void k_softmaxA(const float* __restrict__ tl, float* __restrict__ A) {
    int row = blockIdx.x;                       // m*512 + i
    const float* x = tl + (size_t)row * MQ;
    float* y = A + (size_t)row * MQ;
    int tid = threadIdx.x;                      // 256 threads
    float v0 = x[tid], v1 = x[tid + 256];
    float mx = fmaxf(v0, v1);
    #pragma unroll
    for (int d = 32; d >= 1; d >>= 1) mx = fmaxf(mx, __shfl_xor(mx, d));
    __shared__ float sm[4], ss[4];
    int w = tid >> 6;
    if ((tid & 63) == 0) sm[w] = mx;
    __syncthreads();
    mx = fmaxf(fmaxf(sm[0], sm[1]), fmaxf(sm[2], sm[3]));
    float e0 = expf(v0 - mx), e1 = expf(v1 - mx);
    float s = e0 + e1;
    #pragma unroll
    for (int d = 32; d >= 1; d >>= 1) s += __shfl_xor(s, d);
    if ((tid & 63) == 0) ss[w] = s;
    __syncthreads();
    s = ss[0] + ss[1] + ss[2] + ss[3];
    float inv = 1.0f / s;
    y[tid] = e0 * inv;
    y[tid + 256] = e1 * inv;
}

// ---------------- tiled transpose A -> AT ----------------
__global__ void k_transpose(const float* __restrict__ A, float* __restrict__ AT) {
    __shared__ float tile[64][65];
    int m = blockIdx.z;
    int i0 = blockIdx.x * 64, j0 = blockIdx.y * 64;
    int tx = threadIdx.x, ty = threadIdx.y;     // (64,4)
    for (int r = ty; r < 64; r += 4)
        tile[r][tx] = A[((size_t)(m*MQ + i0 + r))*MQ + j0 + tx];
    __syncthreads();
    for (int r = ty; r < 64; r += 4)
        AT[((size_t)(m*MQ + j0 + r))*MQ + i0 + tx] = tile[tx][r];
}

// ---------------- emission softmax (B) + init softmax ----------------
__global__ void k_bprep(const float* __restrict__ emis, const float* __restrict__ initl,
                        float* __restrict__ Bmat, float* __restrict__ initp) {
    int m = blockIdx.x;
    int q = threadIdx.x;                        // 512 threads
    const float* er = emis + ((size_t)(m*MQ) + q) * MS;
    float tv[MS];
    float mx = -1e30f;
    #pragma unroll
    for (int s = 0; s < MS; s++) { tv[s] = er[s]; mx = fmaxf(mx, tv[s]); }
    float sum = 0.f;
    #pragma unroll
    for (int s = 0; s < MS; s++) { tv[s] = expf(tv[s] - mx); sum += tv[s]; }
    float inv = 1.f / sum;
    float* bo = Bmat + ((size_t)(m*MQ) + q) * MS;
    #pragma unroll
    for (int s = 0; s < MS; s++) bo[s] = tv[s] * inv;

    // init logits softmax over q=512 (block-wide)
    __shared__ float red2[8];
    float v = initl[m*MQ + q];
    float mx2 = v;
    #pragma unroll
    for (int d = 32; d >= 1; d >>= 1) mx2 = fmaxf(mx2, __shfl_xor(mx2, d));
    if ((q & 63) == 0) red2[q >> 6] = mx2;
    __syncthreads();
    mx2 = red2[0];
    #pragma unroll
    for (int k = 1; k < 8; k++) mx2 = fmaxf(mx2, red2[k]);
    float e = expf(v - mx2);
    float s2 = e;
    #pragma unroll
    for (int d = 32; d >= 1; d >>= 1) s2 += __shfl_xor(s2, d);
    __syncthreads();                            // protect red2 reuse
    if ((q & 63) == 0) red2[q >> 6] = s2;
    __syncthreads();
    s2 = 0.f;
    #pragma unroll
    for (int k = 0; k < 8; k++) s2 += red2[k];
    initp[m*MQ + q] = e / s2;
}

// ---------------- E[m,b,l,q] = sum_s inputs[m,b,l,s]*B[m,q,s] + EPS ----------------
__global__ void k_ekernel(const float* __restrict__ inp, const float* __restrict__ Bmat,
                          float* __restrict__ E) {
    int lc = blockIdx.x, b = blockIdx.y, m = blockIdx.z;
    int tid = threadIdx.x;                      // 512
    __shared__ float Bl[MQ * MS];               // 53KB
    __shared__ float xl[8 * MS];
    for (int k = tid; k < MQ * MS; k += 512) Bl[k] = Bmat[(size_t)m * MQ * MS + k];
    int l0 = lc * 8;
    const float* xin = inp + (((size_t)(m*MB + b) * ML + l0) * MS);
    for (int k = tid; k < 8 * MS; k += 512) xl[k] = xin[k];
    __syncthreads();
    float* Eo = E + (((size_t)(m*MB + b) * ML + l0) * MQ);
    const float* br = Bl + tid * MS;
    for (int l = 0; l < 8; l++) {
        float acc = 1e-16f;
        const float* xr = xl + l * MS;
        #pragma unroll
        for (int s = 0; s < MS; s++) acc = fmaf(br[s], xr[s], acc);
        Eo[l * MQ + tid] = acc;
    }
}

// ---------------- fused forward / backward (one block per (dir, m, b-pair)) ----------------
__device__ __forceinline__ int sidx(int i) { return ((i >> 6) * 66 + (i & 63)) * 2; }

__global__ __launch_bounds__(512) void k_fwdbwd(
    const float* __restrict__ A, const float* __restrict__ AT,
    const float* __restrict__ E, const float* __restrict__ initp,
    float* __restrict__ P1, float* __restrict__ out, float* __restrict__ llws)
{
    const int bid  = blockIdx.x;
    const int dir  = bid & 1;
    const int m    = (bid >> 1) & 1;
    const int bp   = bid >> 2;                  // 0..15
    const int b0   = bp * 2;

    const int tid  = threadIdx.x;
    const int w    = tid >> 6;
    const int lane = tid & 63;
    const int gi   = lane >> 3;
    const int jl   = lane & 7;
    const int j0   = w * 64 + jl * 8;           // output octet base

    __shared__ __align__(16) float st[1056];    // state, 2 seqs interleaved, 66-padded
    __shared__ __align__(16) float wl[1056];    // bwd weighted vector
    __shared__ float red[16];

    const size_t eb0 = ((size_t)(m*MB + b0)     * ML) * MQ;
    const size_t eb1 = ((size_t)(m*MB + b0 + 1) * ML) * MQ;
    const float* Am  = A  + (size_t)m * MQ * MQ;
    const float* ATm = AT + (size_t)m * MQ * MQ;

    if (dir == 0) {
        // ================= forward =================
        float C0, C1;
        {   // t = 0
            int j = tid;
            float ip = initp[m*MQ + j];
            float a0 = ip * E[eb0 + j];
            float a1 = ip * E[eb1 + j];
            float p0 = a0, p1 = a1;
            #pragma unroll
            for (int d = 32; d >= 1; d >>= 1) { p0 += __shfl_xor(p0, d); p1 += __shfl_xor(p1, d); }
            if (lane == 0) { red[w*2] = p0; red[w*2+1] = p1; }
            __syncthreads();
            float c0 = 0.f, c1 = 0.f;
            #pragma unroll
            for (int k = 0; k < 8; k++) { c0 += red[k*2]; c1 += red[k*2+1]; }
            float i0v = 1.f/c0, i1v = 1.f/c1;
            C0 = __logf(c0); C1 = __logf(c1);
            float ah0 = a0 * i0v, ah1 = a1 * i1v;
            int si = sidx(j);
            st[si] = ah0; st[si+1] = ah1;
            P1[eb0 + j] = __logf(ah0) + C0;
            P1[eb1 + j] = __logf(ah1) + C1;
            __syncthreads();
        }
        for (int t = 1; t < ML; ++t) {
            float u[2][8];
            #pragma unroll
            for (int k = 0; k < 8; k++) { u[0][k] = 0.f; u[1][k] = 0.f; }
            const float* ap = Am + (size_t)(gi*64) * MQ + j0;
            const float* sp = st + gi * 132;
            #pragma unroll 4
            for (int it = 0; it < 64; it += 2) {
                float4 al = *(const float4*)(sp + it*2);     // a0_i,a1_i,a0_i1,a1_i1
                float r[8];
                *(float4*)&r[0] = *(const float4*)(ap);
                *(float4*)&r[4] = *(const float4*)(ap + 4);
                #pragma unroll
                for (int k = 0; k < 8; k++) { u[0][k] = fmaf(al.x, r[k], u[0][k]);
                                              u[1][k] = fmaf(al.y, r[k], u[1][k]); }
                *(float4*)&r[0] = *(const float4*)(ap + MQ);
                *(float4*)&r[4] = *(const float4*)(ap + MQ + 4);
                #pragma unroll
                for (int k = 0; k < 8; k++) { u[0][k] = fmaf(al.z, r[k], u[0][k]);
                                              u[1][k] = fmaf(al.w, r[k], u[1][k]); }
                ap += 2 * MQ;
            }
            // reduce partials over the 8 i-groups (lane stride 8)
            #pragma unroll
            for (int d = 8; d <= 32; d <<= 1) {
                #pragma unroll
                for (int k = 0; k < 8; k++) { u[0][k] += __shfl_xor(u[0][k], d);
                                              u[1][k] += __shfl_xor(u[1][k], d); }
            }
            const float* e0p = E + eb0 + (size_t)t * MQ + j0;
            const float* e1p = E + eb1 + (size_t)t * MQ + j0;
            float e0[8], e1[8], a0[8], a1[8];
            *(float4*)&e0[0] = *(const float4*)(e0p);
            *(float4*)&e0[4] = *(const float4*)(e0p + 4);
            *(float4*)&e1[0] = *(const float4*)(e1p);
            *(float4*)&e1[4] = *(const float4*)(e1p + 4);
            float pc0 = 0.f, pc1 = 0.f;
            #pragma unroll
            for (int k = 0; k < 8; k++) {
                a0[k] = u[0][k] * e0[k]; pc0 += a0[k];
                a1[k] = u[1][k] * e1[k]; pc1 += a1[k];
            }
            #pragma unroll
            for (int d = 1; d <= 4; d <<= 1) { pc0 += __shfl_xor(pc0, d); pc1 += __shfl_xor(pc1, d); }
            if (lane == 0) { red[w*2] = pc0; red[w*2+1] = pc1; }
            __syncthreads();
            float c0 = 0.f, c1 = 0.f;
            #pragma unroll
            for (int k = 0; k < 8; k++) { c0 += red[k*2]; c1 += red[k*2+1]; }
            float ic0 = 1.f/c0, ic1 = 1.f/c1;
            C0 += __logf(c0); C1 += __logf(c1);
            if (gi == 0) {
                float* so = st + w*132 + jl*16;
                float o0[8], o1[8];
                #pragma unroll
                for (int k = 0; k < 8; k++) {
                    float v0 = a0[k] * ic0, v1 = a1[k] * ic1;
                    so[k*2] = v0; so[k*2+1] = v1;
                    o0[k] = __logf(v0) + C0; o1[k] = __logf(v1) + C1;
                }
                float* p0o = P1 + eb0 + (size_t)t * MQ + j0;
                float* p1o = P1 + eb1 + (size_t)t * MQ + j0;
                *(float4*)(p0o)     = *(float4*)&o0[0];
                *(float4*)(p0o + 4) = *(float4*)&o0[4];
                *(float4*)(p1o)     = *(float4*)&o1[0];
                *(float4*)(p1o + 4) = *(float4*)&o1[4];
            }
            __syncthreads();
        }
        if (tid == 0) {
            llws[m*MB + b0]     = C0;
            llws[m*MB + b0 + 1] = C1;
            out[NPOST + m*MB + b0]     = C0;
            out[NPOST + m*MB + b0 + 1] = C1;
        }
    } else {
        // ================= backward =================
        float D0 = 0.f, D1 = 0.f;
        {   // t = L-1: beta_hat = 1, P2 = 0
            int j = tid;
            int si = sidx(j);
            st[si] = 1.f; st[si+1] = 1.f;
            out[eb0 + (size_t)(ML-1) * MQ + j] = 0.f;
            out[eb1 + (size_t)(ML-1) * MQ + j] = 0.f;
            __syncthreads();
        }
        for (int t = ML - 2; t >= 0; --t) {
            {   // w = E[t+1] .* beta_hat
                int j = tid;
                int si = sidx(j);
                float bv0 = st[si], bv1 = st[si+1];
                wl[si]   = bv0 * E[eb0 + (size_t)(t+1) * MQ + j];
                wl[si+1] = bv1 * E[eb1 + (size_t)(t+1) * MQ + j];
            }
            __syncthreads();
            float u[2][8];
            #pragma unroll
            for (int k = 0; k < 8; k++) { u[0][k] = 0.f; u[1][k] = 0.f; }
            const float* ap = ATm + (size_t)(gi*64) * MQ + j0;   // rows = j (sum), cols = i (output)
            const float* sp = wl + gi * 132;
            #pragma unroll 4
            for (int it = 0; it < 64; it += 2) {
                float4 al = *(const float4*)(sp + it*2);
                float r[8];
                *(float4*)&r[0] = *(const float4*)(ap);
                *(float4*)&r[4] = *(const float4*)(ap + 4);
                #pragma unroll
                for (int k = 0; k < 8; k++) { u[0][k] = fmaf(al.x, r[k], u[0][k]);
                                              u[1][k] = fmaf(al.y, r[k], u[1][k]); }
                *(float4*)&r[0] = *(const float4*)(ap + MQ);
                *(float4*)&r[4] = *(const float4*)(ap + MQ + 4);
                #pragma unroll
                for (int k = 0; k < 8; k++) { u[0][k] = fmaf(al.z, r[k], u[0][k]);
                                              u[1][k] = fmaf(al.w, r[k], u[1][k]); }
                ap += 2 * MQ;
            }
            #pragma unroll
            for (int d = 8; d <= 32; d <<= 1) {
                #pragma unroll
                for (int k = 0; k < 8; k++) { u[0][k] += __shfl_xor(u[0][k], d);
                                              u[1][k] += __shfl_xor(u[1][k], d); }
            }
            float pc0 = 0.f, pc1 = 0.f;
            #pragma unroll
            for (int k = 0; k < 8; k++) { pc0 += u[0][k]; pc1 += u[1][k]; }
            #pragma unroll
            for (int d = 1; d <= 4; d <<= 1) { pc0 += __shfl_xor(pc0, d); pc1 += __shfl_xor(pc1, d); }
            if (lane == 0) { red[w*2] = pc0; red[w*2+1] = pc1; }
            __syncthreads();
            float c0 = 0.f, c1 = 0.f;
            #pragma unroll
            for (int k = 0; k < 8; k++) { c0 += red[k*2]; c1 += red[k*2+1]; }
            float ic0 = 1.f/c0, ic1 = 1.f/c1;
            D0 += __logf(c0); D1 += __logf(c1);
            if (gi == 0) {
                float* so = st + w*132 + jl*16;
                float o0[8], o1[8];
                #pragma unroll
                for (int k = 0; k < 8; k++) {
                    float v0 = u[0][k] * ic0, v1 = u[1][k] * ic1;
                    so[k*2] = v0; so[k*2+1] = v1;
                    o0[k] = __logf(v0) + D0; o1[k] = __logf(v1) + D1;
                }
                float* q0o = out + eb0 + (size_t)t * MQ + j0;
                float* q1o = out + eb1 + (size_t)t * MQ + j0;
                *(float4*)(q0o)     = *(float4*)&o0[0];
                *(float4*)(q0o + 4) = *(float4*)&o0[4];
                *(float4*)(q1o)     = *(float4*)&o1[0];
                *(float4*)(q1o + 4) = *(float4*)&o1[4];
            }
            __syncthreads();
        }
    }
}

// ---------------- combine: out = P2(out) + P1 - loglik ----------------
__global__ void k_combine(const float* __restrict__ P1, const float* __restrict__ llws,
                          float* __restrict__ out) {
    size_t idx = ((size_t)blockIdx.x * 256 + threadIdx.x) * 4;
    int mb = (int)(idx >> 18);                  // L*Q = 262144 per (m,b)
    float ll = llws[mb];
    float4 p = *(const float4*)(P1 + idx);
    float4 o = *(const float4*)(out + idx);
    o.x = o.x + p.x - ll;
    o.y = o.y + p.y - ll;
    o.z = o.z + p.z - ll;
    o.w = o.w + p.w - ll;
    *(float4*)(out + idx) = o;
}

extern "C" void kernel_launch(void* const* d_in, const int* in_sizes, int n_in,
                              void* d_out, int out_size, void* d_ws, size_t ws_size,
                              hipStream_t stream) {
    (void)in_sizes; (void)n_in; (void)out_size; (void)ws_size;
    const float* inp   = (const float*)d_in[0];
    const float* trans = (const float*)d_in[1];
    const float* emis  = (const float*)d_in[2];
    const float* initl = (const float*)d_in[3];
    float* out = (float*)d_out;
    float* ws  = (float*)d_ws;

    float* wsA    = ws + OFF_A;
    float* wsAT   = ws + OFF_AT;
    float* wsB    = ws + OFF_B;
    float* wsInit = ws + OFF_INIT;
    float* wsE    = ws + OFF_E;
    float* wsP1   = ws + OFF_P1;
    float* wsLL   = ws + OFF_LL;

    k_softmaxA<<<MM*MQ, 256, 0, stream>>>(trans, wsA);
    k_transpose<<<dim3(8,8,MM), dim3(64,4), 0, stream>>>(wsA, wsAT);
    k_bprep<<<MM, 512, 0, stream>>>(emis, initl, wsB, wsInit);
    k_ekernel<<<dim3(ML/8, MB, MM), 512, 0, stream>>>(inp, wsB, wsE);
    k_fwdbwd<<<64, 512, 0, stream>>>(wsA, wsAT, wsE, wsInit, wsP1, out, wsLL);
    k_combine<<<NPOST/1024, 256, 0, stream>>>(wsP1, wsLL, out);
}

// Round 3
// 3261.310 us; speedup vs baseline: 1.5401x; 1.5401x over previous
//
#include <hip/hip_runtime.h>
#include <math.h>

#define MQ 512           // states q
#define ML 512           // sequence length L
#define MS 26            // symbols
#define MB 32            // batch
#define MM 2             // models
#define NPOST (MM*MB*ML*MQ)   // 16777216

// ws layout (floats)
#define OFF_A    0
#define OFF_APK  (OFF_A + MM*MQ*MQ)         // uint32: [m][256 pairs][512 j]
#define OFF_ATPK (OFF_APK + MM*256*MQ)
#define OFF_B    (OFF_ATPK + MM*256*MQ)
#define OFF_INIT (OFF_B + MM*MQ*MS)
#define OFF_E    (OFF_INIT + MM*MQ)
#define OFF_P1   (OFF_E + NPOST)
#define OFF_LL   (OFF_P1 + NPOST)

#define LOG16f   2.7725887222397811f
#define LOG4096f 8.3177661667193433f

typedef _Float16 halfx2 __attribute__((ext_vector_type(2)));

#define BCH(x) __builtin_bit_cast(halfx2, (unsigned)(x))

#if __has_builtin(__builtin_amdgcn_fdot2)
#define FDOT2(a,b,c) __builtin_amdgcn_fdot2((a),(b),(c),false)
#else
static __device__ __forceinline__ float FDOT2(halfx2 a, halfx2 b, float c){
  return fmaf((float)a.x,(float)b.x, fmaf((float)a.y,(float)b.y,c));
}
#endif

#if __has_builtin(__builtin_amdgcn_cvt_pkrtz)
#define PKU(x,y) __builtin_bit_cast(unsigned, __builtin_amdgcn_cvt_pkrtz((x),(y)))
#else
static __device__ __forceinline__ unsigned PKU(float x, float y){
  halfx2 r; r.x=(_Float16)x; r.y=(_Float16)y; return __builtin_bit_cast(unsigned, r);
}
#endif

// ---------------- row softmax of transition logits -> A (prob domain) ----------------
__global__ void k_softmaxA(const float* __restrict__ tl, float* __restrict__ A) {
    int row = blockIdx.x;                       // m*512 + i
    const float* x = tl + (size_t)row * MQ;
    float* y = A + (size_t)row * MQ;
    int tid = threadIdx.x;                      // 256 threads
    float v0 = x[tid], v1 = x[tid + 256];
    float mx = fmaxf(v0, v1);
    #pragma unroll
    for (int d = 32; d >= 1; d >>= 1) mx = fmaxf(mx, __shfl_xor(mx, d));
    __shared__ float sm[4], ss[4];
    int w = tid >> 6;
    if ((tid & 63) == 0) sm[w] = mx;
    __syncthreads();
    mx = fmaxf(fmaxf(sm[0], sm[1]), fmaxf(sm[2], sm[3]));
    float e0 = expf(v0 - mx), e1 = expf(v1 - mx);
    float s = e0 + e1;
    #pragma unroll
    for (int d = 32; d >= 1; d >>= 1) s += __shfl_xor(s, d);
    if ((tid & 63) == 0) ss[w] = s;
    __syncthreads();
    s = ss[0] + ss[1] + ss[2] + ss[3];
    float inv = 1.0f / s;
    y[tid] = e0 * inv;
    y[tid + 256] = e1 * inv;
}

// ---------------- pack A (prob fp32) -> fp16 pairs along i, scaled x16 ----------------
__global__ void k_packA(const float* __restrict__ A, unsigned* __restrict__ Apk) {
    int P = blockIdx.x, m = blockIdx.y, j = threadIdx.x;   // 512 threads
    const float* s = A + ((size_t)(m*MQ) + 2*P) * MQ;
    float x0 = s[j] * 16.f, x1 = s[MQ + j] * 16.f;
    halfx2 r; r.x = (_Float16)x0; r.y = (_Float16)x1;
    Apk[((size_t)m*256 + P) * MQ + j] = __builtin_bit_cast(unsigned, r);
}

// ---------------- transpose A and pack pairs along j (for backward), scaled x16 -------
__global__ void k_transposePack(const float* __restrict__ A, unsigned* __restrict__ ATpk) {
    __shared__ float tile[64][65];
    int m = blockIdx.z;
    int i0 = blockIdx.x * 64, j0 = blockIdx.y * 64;
    int tx = threadIdx.x, ty = threadIdx.y;     // (64,4)
    for (int r = ty; r < 64; r += 4)
        tile[r][tx] = A[((size_t)(m*MQ + i0 + r))*MQ + j0 + tx];
    __syncthreads();
    for (int rp = ty; rp < 32; rp += 4) {
        float x0 = tile[tx][2*rp]   * 16.f;
        float x1 = tile[tx][2*rp+1] * 16.f;
        halfx2 r; r.x = (_Float16)x0; r.y = (_Float16)x1;
        ATpk[((size_t)m*256 + (j0>>1) + rp) * MQ + i0 + tx] = __builtin_bit_cast(unsigned, r);
    }
}

// ---------------- emission softmax (B) + init softmax ----------------
__global__ void k_bprep(const float* __restrict__ emis, const float* __restrict__ initl,
                        float* __restrict__ Bmat, float* __restrict__ initp) {
    int m = blockIdx.x;
    int q = threadIdx.x;                        // 512 threads
    const float* er = emis + ((size_t)(m*MQ) + q) * MS;
    float tv[MS];
    float mx = -1e30f;
    #pragma unroll
    for (int s = 0; s < MS; s++) { tv[s] = er[s]; mx = fmaxf(mx, tv[s]); }
    float sum = 0.f;
    #pragma unroll
    for (int s = 0; s < MS; s++) { tv[s] = expf(tv[s] - mx); sum += tv[s]; }
    float inv = 1.f / sum;
    float* bo = Bmat + ((size_t)(m*MQ) + q) * MS;
    #pragma unroll
    for (int s = 0; s < MS; s++) bo[s] = tv[s] * inv;

    __shared__ float red2[8];
    float v = initl[m*MQ + q];
    float mx2 = v;
    #pragma unroll
    for (int d = 32; d >= 1; d >>= 1) mx2 = fmaxf(mx2, __shfl_xor(mx2, d));
    if ((q & 63) == 0) red2[q >> 6] = mx2;
    __syncthreads();
    mx2 = red2[0];
    #pragma unroll
    for (int k = 1; k < 8; k++) mx2 = fmaxf(mx2, red2[k]);
    float e = expf(v - mx2);
    float s2 = e;
    #pragma unroll
    for (int d = 32; d >= 1; d >>= 1) s2 += __shfl_xor(s2, d);
    __syncthreads();
    if ((q & 63) == 0) red2[q >> 6] = s2;
    __syncthreads();
    s2 = 0.f;
    #pragma unroll
    for (int k = 0; k < 8; k++) s2 += red2[k];
    initp[m*MQ + q] = e / s2;
}

// ---------------- E[m,b,l,q] = sum_s inputs[m,b,l,s]*B[m,q,s] + EPS ----------------
__global__ void k_ekernel(const float* __restrict__ inp, const float* __restrict__ Bmat,
                          float* __restrict__ E) {
    int lc = blockIdx.x, b = blockIdx.y, m = blockIdx.z;
    int tid = threadIdx.x;                      // 512
    __shared__ float Bl[MQ * MS];               // 53KB
    __shared__ float xl[8 * MS];
    for (int k = tid; k < MQ * MS; k += 512) Bl[k] = Bmat[(size_t)m * MQ * MS + k];
    int l0 = lc * 8;
    const float* xin = inp + (((size_t)(m*MB + b) * ML + l0) * MS);
    for (int k = tid; k < 8 * MS; k += 512) xl[k] = xin[k];
    __syncthreads();
    float* Eo = E + (((size_t)(m*MB + b) * ML + l0) * MQ);
    const float* br = Bl + tid * MS;
    for (int l = 0; l < 8; l++) {
        float acc = 1e-16f;
        const float* xr = xl + l * MS;
        #pragma unroll
        for (int s = 0; s < MS; s++) acc = fmaf(br[s], xr[s], acc);
        Eo[l * MQ + tid] = acc;
    }
}

// ---------------- fused fwd/bwd: 64 blocks (dir,m,bpair) x 256 threads, 2 chains ------
// Per-lane tile: 64 i (32 fp16 pairs) x 16 j, shared by both chains.
// Pairs 0..21 in VGPRs, 22..24 in LDS slabs, 25..31 streamed from L2 each step.
// lane = ig*8+jg (wave w); wave owns j in [128w,128w+128); lane i-range [64ig,64ig+64).
// After butterfly over ig, lane owns j = jown, jown+1 for both chains.

#define NREGP 22
#define SLAB_ROWS 24           // 8 ig * 3 pairs (22,23,24)
#define SLAB_STR  524          // stride%32=12 -> conflict-free b128
#define ABASE (SLAB_ROWS*SLAB_STR)    // 12576
#define ACH   288                     // per-chain alpha region (8 groups * 36)
#define RBASE (ABASE + 2*ACH)         // 13152
#define SHM_DW (RBASE + 16)           // 13168 dwords = 52672 B

#define D2C(idx, AW) { u0[idx]=FDOT2(BCH(AW),_ah0,u0[idx]); u1[idx]=FDOT2(BCH(AW),_ah1,u1[idx]); }

#define DOT16_2(A0,A1,A2,A3, AD0, AD1) do { halfx2 _ah0 = BCH(AD0), _ah1 = BCH(AD1); \
  D2C(0,(A0).x)  D2C(1,(A0).y)  D2C(2,(A0).z)  D2C(3,(A0).w)                         \
  D2C(4,(A1).x)  D2C(5,(A1).y)  D2C(6,(A1).z)  D2C(7,(A1).w)                         \
  D2C(8,(A2).x)  D2C(9,(A2).y)  D2C(10,(A2).z) D2C(11,(A2).w)                        \
  D2C(12,(A3).x) D2C(13,(A3).y) D2C(14,(A3).z) D2C(15,(A3).w)                        \
} while(0)

#define LOADSV(DST, PI) do {                                                  \
  DST[0] = gM4[((PI)*128) + wj4 + 0]; DST[1] = gM4[((PI)*128) + wj4 + 1];     \
  DST[2] = gM4[((PI)*128) + wj4 + 2]; DST[3] = gM4[((PI)*128) + wj4 + 3];     \
} while(0)

// matvec + reduce: MV00,MV01 = chain0 column sums at j=jown,jown+1; MV10,MV11 chain1
#define MATVEC(MV00, MV01, MV10, MV11) do {                                   \
  float u0[16], u1[16];                                                       \
  _Pragma("unroll") for (int k=0;k<16;k++){ u0[k]=0.f; u1[k]=0.f; }           \
  uint4 sv0[4],sv1[4],sv2[4],sv3[4],sv4[4],sv5[4],sv6[4];                     \
  uint4 t0, t1, avh0, avh1, avh20, avh21;                                     \
  _Pragma("unroll")                                                           \
  for (int p=0;p<NREGP;++p){                                                  \
    if ((p&3)==0){ t0 = *(const uint4*)(shm + ABASE + ig*36 + p);             \
                   t1 = *(const uint4*)(shm + ABASE + ACH + ig*36 + p); }     \
    if (p==8){ avh0  = *(const uint4*)(shm + ABASE + ig*36 + 24);             \
               avh20 = *(const uint4*)(shm + ABASE + ig*36 + 28);             \
               avh1  = *(const uint4*)(shm + ABASE + ACH + ig*36 + 24);       \
               avh21 = *(const uint4*)(shm + ABASE + ACH + ig*36 + 28); }     \
    if (p==0)  LOADSV(sv0, ig*32+25);                                         \
    if (p==3)  LOADSV(sv1, ig*32+26);                                         \
    if (p==6)  LOADSV(sv2, ig*32+27);                                         \
    if (p==9)  LOADSV(sv3, ig*32+28);                                         \
    if (p==12) LOADSV(sv4, ig*32+29);                                         \
    if (p==15) LOADSV(sv5, ig*32+30);                                         \
    if (p==18) LOADSV(sv6, ig*32+31);                                         \
    unsigned ad0 = ((p&3)==0)?t0.x:((p&3)==1)?t0.y:((p&3)==2)?t0.z:t0.w;      \
    unsigned ad1 = ((p&3)==0)?t1.x:((p&3)==1)?t1.y:((p&3)==2)?t1.z:t1.w;      \
    DOT16_2(Ar[p*4+0],Ar[p*4+1],Ar[p*4+2],Ar[p*4+3], ad0, ad1);               \
    if (p==10) DOT16_2(sv0[0],sv0[1],sv0[2],sv0[3], avh0.y, avh1.y);          \
    if (p==12) DOT16_2(sv1[0],sv1[1],sv1[2],sv1[3], avh0.z, avh1.z);          \
    if (p==14) DOT16_2(sv2[0],sv2[1],sv2[2],sv2[3], avh0.w, avh1.w);          \
    if (p==16) DOT16_2(sv3[0],sv3[1],sv3[2],sv3[3], avh20.x, avh21.x);        \
    if (p==18) DOT16_2(sv4[0],sv4[1],sv4[2],sv4[3], avh20.y, avh21.y);        \
    if (p==20) DOT16_2(sv5[0],sv5[1],sv5[2],sv5[3], avh20.z, avh21.z);        \
  }                                                                           \
  _Pragma("unroll")                                                           \
  for (int s=0;s<3;++s){                                                      \
    const unsigned* sb = shm + (ig*3+s)*SLAB_STR + wbase + jg*16;             \
    uint4 sd0 = *(const uint4*)(sb + 0);                                      \
    uint4 sd1 = *(const uint4*)(sb + 4);                                      \
    uint4 sd2 = *(const uint4*)(sb + 8);                                      \
    uint4 sd3 = *(const uint4*)(sb + 12);                                     \
    unsigned ad0 = (s==0)?t0.z:((s==1)?t0.w:avh0.x);                          \
    unsigned ad1 = (s==0)?t1.z:((s==1)?t1.w:avh1.x);                          \
    DOT16_2(sd0,sd1,sd2,sd3, ad0, ad1);                                       \
    if (s==0) DOT16_2(sv6[0],sv6[1],sv6[2],sv6[3], avh20.w, avh21.w);         \
  }                                                                           \
  float v8a[8], v8b[8];                                                       \
  { const int h=(ig>>2)&1;                                                    \
    _Pragma("unroll") for (int k=0;k<8;k++){                                  \
      float ma = h?u0[k+8]:u0[k];  float oa = h?u0[k]:u0[k+8];                \
      v8a[k] = ma + __shfl_xor(oa,32);                                        \
      float mb = h?u1[k+8]:u1[k];  float ob = h?u1[k]:u1[k+8];                \
      v8b[k] = mb + __shfl_xor(ob,32); } }                                    \
  float v4a[4], v4b[4];                                                       \
  { const int h=(ig>>1)&1;                                                    \
    _Pragma("unroll") for (int k=0;k<4;k++){                                  \
      float ma = h?v8a[k+4]:v8a[k]; float oa = h?v8a[k]:v8a[k+4];             \
      v4a[k] = ma + __shfl_xor(oa,16);                                        \
      float mb = h?v8b[k+4]:v8b[k]; float ob = h?v8b[k]:v8b[k+4];             \
      v4b[k] = mb + __shfl_xor(ob,16); } }                                    \
  { const int h=ig&1;                                                         \
    float m0 = h?v4a[2]:v4a[0], o0 = h?v4a[0]:v4a[2];                         \
    float m1 = h?v4a[3]:v4a[1], o1 = h?v4a[1]:v4a[3];                         \
    MV00 = m0 + __shfl_xor(o0,8); MV01 = m1 + __shfl_xor(o1,8);               \
    float m2 = h?v4b[2]:v4b[0], o2 = h?v4b[0]:v4b[2];                         \
    float m3 = h?v4b[3]:v4b[1], o3 = h?v4b[1]:v4b[3];                         \
    MV10 = m2 + __shfl_xor(o2,8); MV11 = m3 + __shfl_xor(o3,8); }             \
} while(0)

__global__ __launch_bounds__(256, 1) void k_fwdbwd(
    const unsigned* __restrict__ Apk, const unsigned* __restrict__ ATpk,
    const float* __restrict__ E, const float* __restrict__ initp,
    float* __restrict__ P1, float* __restrict__ out, float* __restrict__ llws)
{
    __shared__ __align__(16) unsigned shm[SHM_DW];
    const int bid = blockIdx.x;
    const int dir = bid & 1, m = (bid >> 1) & 1;
    const int b0 = (bid >> 2) * 2;
    const int tid = threadIdx.x;
    const int w = tid >> 6, lane = tid & 63;
    const int ig = lane >> 3, jg = lane & 7;
    const int wbase = w * 128;
    const int jown = wbase + jg*16 + ig*2;
    const int wj4 = (wbase + jg*16) >> 2;
    const int Pown = jown >> 1;
    const int aown = (Pown >> 5)*36 + (Pown & 31);

    const unsigned* gM = (dir ? ATpk : Apk) + (size_t)m * (256*MQ);
    const uint4* gM4 = (const uint4*)gM;
    const size_t eb0 = ((size_t)(m*MB + b0))     * ML * MQ;
    const size_t eb1 = ((size_t)(m*MB + b0 + 1)) * ML * MQ;
    const float* Eb0 = E + eb0;
    const float* Eb1 = E + eb1;

    // ---- preload register stash (pairs 0..21) ----
    uint4 Ar[NREGP*4];
    #pragma unroll
    for (int p = 0; p < NREGP; ++p) {
        #pragma unroll
        for (int c = 0; c < 4; ++c)
            Ar[p*4+c] = gM4[(ig*32 + p)*128 + wj4 + c];
    }
    // ---- preload LDS slabs (pairs 22..24 for each ig) ----
    for (int k = tid; k < SLAB_ROWS*512; k += 256) {
        int row = k >> 9, j = k & 511;
        int P = (row/3)*32 + NREGP + (row%3);
        shm[row*SLAB_STR + j] = gM[(size_t)P*MQ + j];
    }
    __syncthreads();

    if (dir == 0) {
        // ================= forward =================
        float C0, C1;
        {   // t = 0
            float2 ip = *(const float2*)(initp + m*MQ + jown);
            float2 e0 = *(const float2*)(Eb0 + jown);
            float2 e1 = *(const float2*)(Eb1 + jown);
            float a00 = ip.x * e0.x, a01 = ip.y * e0.y;
            float a10 = ip.x * e1.x, a11 = ip.y * e1.y;
            float pc0 = a00 + a01, pc1 = a10 + a11;
            #pragma unroll
            for (int d = 1; d <= 32; d <<= 1) { pc0 += __shfl_xor(pc0, d); pc1 += __shfl_xor(pc1, d); }
            if (lane == 0) { shm[RBASE + w*2] = __float_as_uint(pc0);
                             shm[RBASE + w*2 + 1] = __float_as_uint(pc1); }
            __syncthreads();
            uint4 r0 = *(const uint4*)(shm + RBASE);
            uint4 r1 = *(const uint4*)(shm + RBASE + 4);
            float c0 = __uint_as_float(r0.x)+__uint_as_float(r0.z)+__uint_as_float(r1.x)+__uint_as_float(r1.z);
            float c1 = __uint_as_float(r0.y)+__uint_as_float(r0.w)+__uint_as_float(r1.y)+__uint_as_float(r1.w);
            float ic0 = 1.f/c0, ic1 = 1.f/c1;
            C0 = __logf(c0); C1 = __logf(c1);
            float n00 = a00*ic0, n01 = a01*ic0;
            float n10 = a10*ic1, n11 = a11*ic1;
            shm[ABASE + aown]       = PKU(n00, n01);
            shm[ABASE + ACH + aown] = PKU(n10, n11);
            float2 o0; o0.x = __logf(n00) + C0; o0.y = __logf(n01) + C0;
            float2 o1; o1.x = __logf(n10) + C1; o1.y = __logf(n11) + C1;
            *(float2*)(P1 + eb0 + jown) = o0;
            *(float2*)(P1 + eb1 + jown) = o1;
            __syncthreads();
        }
        #pragma unroll 1
        for (int t = 1; t < ML; ++t) {
            float2 e0 = *(const float2*)(Eb0 + (size_t)t*MQ + jown);
            float2 e1 = *(const float2*)(Eb1 + (size_t)t*MQ + jown);
            float mv00, mv01, mv10, mv11;
            MATVEC(mv00, mv01, mv10, mv11);
            float a00 = mv00 * e0.x, a01 = mv01 * e0.y;
            float a10 = mv10 * e1.x, a11 = mv11 * e1.y;
            float pc0 = a00 + a01, pc1 = a10 + a11;
            #pragma unroll
            for (int d = 1; d <= 32; d <<= 1) { pc0 += __shfl_xor(pc0, d); pc1 += __shfl_xor(pc1, d); }
            if (lane == 0) { shm[RBASE + w*2] = __float_as_uint(pc0);
                             shm[RBASE + w*2 + 1] = __float_as_uint(pc1); }
            __syncthreads();
            uint4 r0 = *(const uint4*)(shm + RBASE);
            uint4 r1 = *(const uint4*)(shm + RBASE + 4);
            float c0 = __uint_as_float(r0.x)+__uint_as_float(r0.z)+__uint_as_float(r1.x)+__uint_as_float(r1.z);
            float c1 = __uint_as_float(r0.y)+__uint_as_float(r0.w)+__uint_as_float(r1.y)+__uint_as_float(r1.w);
            float ic0 = 1.f/c0, ic1 = 1.f/c1;
            C0 += __logf(c0) - LOG16f;
            C1 += __logf(c1) - LOG16f;
            float n00 = a00*ic0, n01 = a01*ic0;
            float n10 = a10*ic1, n11 = a11*ic1;
            shm[ABASE + aown]       = PKU(n00, n01);
            shm[ABASE + ACH + aown] = PKU(n10, n11);
            float2 o0; o0.x = __logf(n00) + C0; o0.y = __logf(n01) + C0;
            float2 o1; o1.x = __logf(n10) + C1; o1.y = __logf(n11) + C1;
            *(float2*)(P1 + eb0 + (size_t)t*MQ + jown) = o0;
            *(float2*)(P1 + eb1 + (size_t)t*MQ + jown) = o1;
            __syncthreads();
        }
        if (tid == 0) {
            llws[m*MB + b0]     = C0;
            llws[m*MB + b0 + 1] = C1;
            out[NPOST + m*MB + b0]     = C0;
            out[NPOST + m*MB + b0 + 1] = C1;
        }
    } else {
        // ================= backward =================
        float D0 = 0.f, D1 = 0.f;
        {   // t = L-1: beta_hat = 1, P2 = 0, w-vec = E[L-1]*256
            float2 e0 = *(const float2*)(Eb0 + (size_t)(ML-1)*MQ + jown);
            float2 e1 = *(const float2*)(Eb1 + (size_t)(ML-1)*MQ + jown);
            shm[ABASE + aown]       = PKU(e0.x * 256.f, e0.y * 256.f);
            shm[ABASE + ACH + aown] = PKU(e1.x * 256.f, e1.y * 256.f);
            float2 z; z.x = 0.f; z.y = 0.f;
            *(float2*)(out + eb0 + (size_t)(ML-1)*MQ + jown) = z;
            *(float2*)(out + eb1 + (size_t)(ML-1)*MQ + jown) = z;
            __syncthreads();
        }
        #pragma unroll 1
        for (int t = ML-2; t >= 0; --t) {
            float2 e0 = *(const float2*)(Eb0 + (size_t)t*MQ + jown);
            float2 e1 = *(const float2*)(Eb1 + (size_t)t*MQ + jown);
            float mv00, mv01, mv10, mv11;
            MATVEC(mv00, mv01, mv10, mv11);
            float pc0 = mv00 + mv01, pc1 = mv10 + mv11;
            #pragma unroll
            for (int d = 1; d <= 32; d <<= 1) { pc0 += __shfl_xor(pc0, d); pc1 += __shfl_xor(pc1, d); }
            if (lane == 0) { shm[RBASE + w*2] = __float_as_uint(pc0);
                             shm[RBASE + w*2 + 1] = __float_as_uint(pc1); }
            __syncthreads();
            uint4 r0 = *(const uint4*)(shm + RBASE);
            uint4 r1 = *(const uint4*)(shm + RBASE + 4);
            float c0 = __uint_as_float(r0.x)+__uint_as_float(r0.z)+__uint_as_float(r1.x)+__uint_as_float(r1.z);
            float c1 = __uint_as_float(r0.y)+__uint_as_float(r0.w)+__uint_as_float(r1.y)+__uint_as_float(r1.w);
            float ic0 = 1.f/c0, ic1 = 1.f/c1;
            D0 += __logf(c0) - LOG4096f;
            D1 += __logf(c1) - LOG4096f;
            float n00 = mv00*ic0, n01 = mv01*ic0;
            float n10 = mv10*ic1, n11 = mv11*ic1;
            shm[ABASE + aown]       = PKU(n00 * e0.x * 256.f, n01 * e0.y * 256.f);
            shm[ABASE + ACH + aown] = PKU(n10 * e1.x * 256.f, n11 * e1.y * 256.f);
            float2 o0; o0.x = __logf(n00) + D0; o0.y = __logf(n01) + D0;
            float2 o1; o1.x = __logf(n10) + D1; o1.y = __logf(n11) + D1;
            *(float2*)(out + eb0 + (size_t)t*MQ + jown) = o0;
            *(float2*)(out + eb1 + (size_t)t*MQ + jown) = o1;
            __syncthreads();
        }
    }
}

// ---------------- combine: out = P2(out) + P1 - loglik ----------------
__global__ void k_combine(const float* __restrict__ P1, const float* __restrict__ llws,
                          float* __restrict__ out) {
    size_t idx = ((size_t)blockIdx.x * 256 + threadIdx.x) * 4;
    int mb = (int)(idx >> 18);                  // L*Q = 262144 per (m,b)
    float ll = llws[mb];
    float4 p = *(const float4*)(P1 + idx);
    float4 o = *(const float4*)(out + idx);
    o.x = o.x + p.x - ll;
    o.y = o.y + p.y - ll;
    o.z = o.z + p.z - ll;
    o.w = o.w + p.w - ll;
    *(float4*)(out + idx) = o;
}

extern "C" void kernel_launch(void* const* d_in, const int* in_sizes, int n_in,
                              void* d_out, int out_size, void* d_ws, size_t ws_size,
                              hipStream_t stream) {
    (void)in_sizes; (void)n_in; (void)out_size; (void)ws_size;
    const float* inp   = (const float*)d_in[0];
    const float* trans = (const float*)d_in[1];
    const float* emis  = (const float*)d_in[2];
    const float* initl = (const float*)d_in[3];
    float* out = (float*)d_out;
    float* ws  = (float*)d_ws;

    float*    wsA    = ws + OFF_A;
    unsigned* wsApk  = (unsigned*)(ws + OFF_APK);
    unsigned* wsATpk = (unsigned*)(ws + OFF_ATPK);
    float*    wsB    = ws + OFF_B;
    float*    wsInit = ws + OFF_INIT;
    float*    wsE    = ws + OFF_E;
    float*    wsP1   = ws + OFF_P1;
    float*    wsLL   = ws + OFF_LL;

    k_softmaxA<<<MM*MQ, 256, 0, stream>>>(trans, wsA);
    k_packA<<<dim3(256, MM), 512, 0, stream>>>(wsA, wsApk);
    k_transposePack<<<dim3(8, 8, MM), dim3(64, 4), 0, stream>>>(wsA, wsATpk);
    k_bprep<<<MM, 512, 0, stream>>>(emis, initl, wsB, wsInit);
    k_ekernel<<<dim3(ML/8, MB, MM), 512, 0, stream>>>(inp, wsB, wsE);
    k_fwdbwd<<<64, 256, 0, stream>>>(wsApk, wsATpk, wsE, wsInit, wsP1, out, wsLL);
    k_combine<<<NPOST/1024, 256, 0, stream>>>(wsP1, wsLL, out);
}